// Round 4
// baseline (454.090 us; speedup 1.0000x reference)
//
#include <hip/hip_runtime.h>

// Sparsemax along last axis of (4, 4096, 4096) fp32 — wave-per-row.
// Row = 4096 elems = 64 lanes x 64 elems (16 float4/lane). Each wave is
// fully independent: NO __syncthreads anywhere (wave-lockstep LDS ordering
// suffices for the per-wave candidate slab + counter).
// tau solves sum(relu(x - tau)) = 1 via Newton from tau0 = max - 1
// (monotone, finite convergence; wave-uniform fixed-point exit).
// Only elements with x > max-1 can ever be active (tau >= max-1): ~14/row
// for Gaussian data -> Newton runs on <=64 lane-resident candidates.

constexpr int D = 4096;
constexpr int BLOCK = 256;
constexpr int WAVES = BLOCK / 64;        // 4 rows per block
constexpr int CHUNKS = D / (64 * 4);     // 16 float4 per lane
constexpr int NEWTON_ITERS = 16;         // hard cap; exits ~6
constexpr int CAP_W = 512;               // per-wave candidate capacity

typedef float v4f __attribute__((ext_vector_type(4)));

__global__ __launch_bounds__(BLOCK) void sparsemax_kernel(
    const float* __restrict__ in, float* __restrict__ out) {
  __shared__ float cand[WAVES][CAP_W];   // 8 KB
  __shared__ int scnt[WAVES];

  const int t = threadIdx.x;
  const int wave = t >> 6;
  const int lane = t & 63;
  const long long row = (long long)blockIdx.x * WAVES + wave;

  const float4* __restrict__ x4 =
      reinterpret_cast<const float4*>(in + row * (long long)D);
  v4f* __restrict__ y4 = reinterpret_cast<v4f*>(out + row * (long long)D);

  // ---- load row slice (coalesced float4: lane + c*64 within the row) ----
  float4 v[CHUNKS];
#pragma unroll
  for (int c = 0; c < CHUNKS; c++) v[c] = x4[lane + c * 64];

  // ---- wave max (butterfly -> all lanes) ----
  float m = -INFINITY;
#pragma unroll
  for (int c = 0; c < CHUNKS; c++)
    m = fmaxf(m, fmaxf(fmaxf(v[c].x, v[c].y), fmaxf(v[c].z, v[c].w)));
#pragma unroll
  for (int o = 32; o > 0; o >>= 1) m = fmaxf(m, __shfl_xor(m, o));
  const float thr = m - 1.0f;  // tau0; no x <= thr can ever be active

  // ---- push candidates into per-wave LDS slab (wave-lockstep: no barrier) --
  if (lane == 0) scnt[wave] = 0;
#pragma unroll
  for (int c = 0; c < CHUNKS; c++) {
    float z;
    z = v[c].x; if (z > thr) { int i = atomicAdd(&scnt[wave], 1); if (i < CAP_W) cand[wave][i] = z; }
    z = v[c].y; if (z > thr) { int i = atomicAdd(&scnt[wave], 1); if (i < CAP_W) cand[wave][i] = z; }
    z = v[c].z; if (z > thr) { int i = atomicAdd(&scnt[wave], 1); if (i < CAP_W) cand[wave][i] = z; }
    z = v[c].w; if (z > thr) { int i = atomicAdd(&scnt[wave], 1); if (i < CAP_W) cand[wave][i] = z; }
  }
  const int n = atomicAdd(&scnt[wave], 0);  // atomic read: ordered after pushes

  // ---- Newton, entirely in-wave (butterfly leaves tau in all lanes) ----
  float tau = thr;
  if (n <= 64) {
    // hot path: one candidate per lane, in-register
    const float sentinel = thr - 1.0f;  // never > tau (tau >= thr)
    float z = (lane < n) ? cand[wave][lane] : sentinel;
    for (int it = 0; it < NEWTON_ITERS; it++) {
      float S = 0.0f, K = 0.0f;
      if (z > tau) { S = z; K = 1.0f; }
#pragma unroll
      for (int o = 32; o > 0; o >>= 1) {
        S += __shfl_xor(S, o);
        K += __shfl_xor(K, o);
      }
      float tnew = (S - 1.0f) / K;  // K >= 1: x_max = m > tau always
      if (tnew == tau) break;       // wave-uniform exit
      tau = tnew;
    }
  } else if (n <= CAP_W) {
    for (int it = 0; it < NEWTON_ITERS; it++) {
      float S = 0.0f, K = 0.0f;
      for (int i = lane; i < n; i += 64) {
        float z = cand[wave][i];
        if (z > tau) { S += z; K += 1.0f; }
      }
#pragma unroll
      for (int o = 32; o > 0; o >>= 1) {
        S += __shfl_xor(S, o);
        K += __shfl_xor(K, o);
      }
      float tnew = (S - 1.0f) / K;
      if (tnew == tau) break;
      tau = tnew;
    }
  } else {
    // fallback: in-wave Newton over the full register slice (never for Gaussian)
    for (int it = 0; it < NEWTON_ITERS; it++) {
      float S = 0.0f, K = 0.0f;
#pragma unroll
      for (int c = 0; c < CHUNKS; c++) {
        float z;
        z = v[c].x; if (z > tau) { S += z; K += 1.0f; }
        z = v[c].y; if (z > tau) { S += z; K += 1.0f; }
        z = v[c].z; if (z > tau) { S += z; K += 1.0f; }
        z = v[c].w; if (z > tau) { S += z; K += 1.0f; }
      }
#pragma unroll
      for (int o = 32; o > 0; o >>= 1) {
        S += __shfl_xor(S, o);
        K += __shfl_xor(K, o);
      }
      float tnew = (S - 1.0f) / K;
      if (tnew == tau) break;
      tau = tnew;
    }
  }

  // ---- write p = max(x - tau, 0), nontemporal float4 (never re-read) ----
#pragma unroll
  for (int c = 0; c < CHUNKS; c++) {
    v4f o;
    o.x = fmaxf(v[c].x - tau, 0.0f);
    o.y = fmaxf(v[c].y - tau, 0.0f);
    o.z = fmaxf(v[c].z - tau, 0.0f);
    o.w = fmaxf(v[c].w - tau, 0.0f);
    __builtin_nontemporal_store(o, y4 + lane + c * 64);
  }
}

extern "C" void kernel_launch(void* const* d_in, const int* in_sizes, int n_in,
                              void* d_out, int out_size, void* d_ws, size_t ws_size,
                              hipStream_t stream) {
  const float* in = (const float*)d_in[0];
  float* out = (float*)d_out;
  const int rows = in_sizes[0] / D;            // 16384
  sparsemax_kernel<<<rows / WAVES, BLOCK, 0, stream>>>(in, out);
}